// Round 7
// baseline (113.271 us; speedup 1.0000x reference)
//
#include <hip/hip_runtime.h>
#include <hip/hip_bf16.h>

typedef __attribute__((ext_vector_type(4))) float  float4v;
typedef __attribute__((ext_vector_type(4))) short  short4v;
typedef __attribute__((ext_vector_type(8))) short  short8v;
typedef __attribute__((ext_vector_type(4))) float  f32x4;

// f32 -> bf16 RTNE via HW cvt (compiler emits v_cvt_pk_bf16_f32)
__device__ __forceinline__ short f2bf(float f) {
  __hip_bfloat16 h = __float2bfloat16(f);
  return *reinterpret_cast<short*>(&h);
}

__device__ __forceinline__ short8v cvt8(float4v v0, float4v v1) {
  short8v s;
  s[0]=f2bf(v0[0]); s[1]=f2bf(v0[1]); s[2]=f2bf(v0[2]); s[3]=f2bf(v0[3]);
  s[4]=f2bf(v1[0]); s[5]=f2bf(v1[1]); s[6]=f2bf(v1[2]); s[7]=f2bf(v1[3]);
  return s;
}

// XOR swizzle for LDS bf16 tiles: short idx k ^= ((row&7)<<3)
__device__ __forceinline__ int swz(int row, int k, int ld) {
  return row * ld + (k ^ ((row & 7) << 3));
}

// async global->LDS, 16B per lane; LDS dest = wave-uniform base + lane*16
__device__ __forceinline__ void gll16(const void* g, void* l) {
  __builtin_amdgcn_global_load_lds(
      (const __attribute__((address_space(1))) unsigned int*)g,
      (__attribute__((address_space(3))) unsigned int*)l, 16, 0, 0);
}

// -------------------------------------------------------------------------
// Kernel 0: wt[f][d] = bf16(W[d][f])  (one-time 128x128 transpose+convert)
// -------------------------------------------------------------------------
__global__ __launch_bounds__(256) void k0_wt(const float* __restrict__ W,
                                             short* __restrict__ wt) {
  const int task = blockIdx.x * 256 + threadIdx.x;   // 2048 tasks
  const int f = task & 127;
  const int dc = (task >> 7) * 8;
  short8v s;
#pragma unroll
  for (int j = 0; j < 8; ++j) s[j] = f2bf(W[(size_t)(dc + j) * 128 + f]);
  *(short8v*)(wt + (size_t)f * 128 + dc) = s;
}

// -------------------------------------------------------------------------
// Kernel 1: ht[b][f][m] = bf16( sum_d feat[b][m][d] * W[d][f] )   (H^T)
// grid (N/64, B), 256 thr. A-frags direct from feat; B-frags direct from
// wt (32 KB, L1-resident). Stores go through an LDS transpose so ht is
// written with fully-coalesced 16B stores (f-row chunks of 64 m).
// -------------------------------------------------------------------------
__global__ __launch_bounds__(256) void k1_feat_x_w(
    const float* __restrict__ feat, const short* __restrict__ wt,
    short* __restrict__ ht, int N) {
  __shared__ short T[128][72];   // [f][m_local], +8 pad (18 KB)
  const int t = threadIdx.x;
  const int batch = blockIdx.y;
  const int m0 = blockIdx.x * 64;
  const int lane = t & 63, wid = t >> 6;
  const int lr = lane & 15, lk = (lane >> 4) * 8;
  const float* pa = feat + (size_t)batch * N * 128
                  + (size_t)(m0 + wid * 16 + lr) * 128 + lk;

  f32x4 acc[8];
#pragma unroll
  for (int j = 0; j < 8; ++j) acc[j] = (f32x4){0.f, 0.f, 0.f, 0.f};

#pragma unroll
  for (int kk = 0; kk < 4; ++kk) {
    float4v v0 = ((const float4v*)(pa + kk * 32))[0];
    float4v v1 = ((const float4v*)(pa + kk * 32))[1];
    short8v a = cvt8(v0, v1);
#pragma unroll
    for (int ni = 0; ni < 8; ++ni) {
      short8v b = *(const short8v*)(wt + (size_t)(ni * 16 + lr) * 128 + kk * 32 + lk);
      acc[ni] = __builtin_amdgcn_mfma_f32_16x16x32_bf16(a, b, acc[ni], 0, 0, 0);
    }
  }

  // deposit: lane holds f=ni*16+lr, m_local = wid*16+(lane>>4)*4+r
  const int mloc = wid * 16 + (lane >> 4) * 4;
#pragma unroll
  for (int ni = 0; ni < 8; ++ni) {
    short4v s;
#pragma unroll
    for (int r = 0; r < 4; ++r) s[r] = f2bf(acc[ni][r]);
    *(short4v*)(&T[ni * 16 + lr][mloc]) = s;
  }
  __syncthreads();

  // coalesced writeout: 1024 (f, m-chunk) slots, 16B each
  short* hb = ht + (size_t)batch * 128 * N;
#pragma unroll
  for (int it = 0; it < 4; ++it) {
    const int idx = it * 256 + t;
    const int f = idx >> 3;
    const int mc = (idx & 7) * 8;
    short8v v = *(const short8v*)(&T[f][mc]);
    *(short8v*)(hb + (size_t)f * N + m0 + mc) = v;
  }
}

// -------------------------------------------------------------------------
// Kernel 2: out[b][m][f] = relu( sum_k A[b][m][k] * H[k][f] + bias[f] )
// grid (N/32, B) = 512 blocks (2 independent blocks/CU), 256 thr = 4 waves.
// Tile 32m x 128f, BK=64; waves at (mi,fj) in 2x2. A is wave-private
// (global->reg->cvt->MFMA, static reg double-buffer); H shared via gll16
// into TRIPLE-buffered LDS, depth-2 prefetch. Sync = raw s_barrier preceded
// by counted `s_waitcnt vmcnt(12)` (per step each wave issues 4 gll + 4
// A-loads, so at body(t) top the 12 newest ops are A(t)+G(t+1)+A(t+1)).
// The pipeline never drains below 8 in-flight vmem ops; the second block
// on the CU covers per-step completion jitter.
// -------------------------------------------------------------------------
__global__ __launch_bounds__(256, 2) void k2_a_x_h(
    const float* __restrict__ A, const short* __restrict__ ht,
    const float* __restrict__ bias, float* __restrict__ out, int N) {
  __shared__ __align__(16) short Hs[3][128 * 64];   // 48 KB
  const int t = threadIdx.x;
  const int lane = t & 63, wid = t >> 6;
  const int mi = wid >> 1, fj = wid & 1;

  // XCD-chunked swizzle (nwg = 512, multiple of 8 -> bijective)
  const int nwg = gridDim.x * gridDim.y;
  int wg = blockIdx.x + gridDim.x * blockIdx.y;
  if ((nwg & 7) == 0) wg = (wg & 7) * (nwg >> 3) + (wg >> 3);
  const int mtiles = gridDim.x;
  const int batch = wg / mtiles;
  const int m0 = (wg - batch * mtiles) * 32;

  const float* Ab = A + (size_t)batch * N * N;
  const short* hb = ht + (size_t)batch * 128 * N;

  const int lr = lane & 15, lk = (lane >> 4) * 8;
  const int hf = lane >> 3, hks = (lane & 7) * 8;   // H stage lane map

  const float* pa = Ab + (size_t)(m0 + mi * 16 + lr) * N + lk;

  // stage 32 f-rows of H (wave's share of the 128-row tile): 4 gll x 1 KB,
  // source pre-swizzled so the linear LDS write lands in swz() layout
  auto stageH = [&](int k0, short* dst) {
#pragma unroll
    for (int i = 0; i < 4; ++i) {
      const int f8 = (wid * 4 + i) * 8;
      const short* g = hb + (size_t)(f8 + hf) * N + k0 + (hks ^ (hf << 3));
      gll16(g, dst + f8 * 64);
    }
  };
  // wave-private A fragments: 16 rows x 64 k -> 4 dwordx4 per lane
  auto loadA = [&](int k0, float4v (&ar)[4]) {
    const float* p = pa + k0;
    ar[0] = ((const float4v*)p)[0];
    ar[1] = ((const float4v*)p)[1];
    ar[2] = ((const float4v*)(p + 32))[0];
    ar[3] = ((const float4v*)(p + 32))[1];
  };

  f32x4 acc[4];
#pragma unroll
  for (int j = 0; j < 4; ++j) acc[j] = (f32x4){0.f, 0.f, 0.f, 0.f};

  auto compute = [&](const short* Hbuf, float4v (&ar)[4]) {
    short8v a0 = cvt8(ar[0], ar[1]);
    short8v a1 = cvt8(ar[2], ar[3]);
#pragma unroll
    for (int ni = 0; ni < 4; ++ni) {
      short8v b = *(const short8v*)(Hbuf + swz(fj * 64 + ni * 16 + lr, lk, 64));
      acc[ni] = __builtin_amdgcn_mfma_f32_16x16x32_bf16(a0, b, acc[ni], 0, 0, 0);
    }
#pragma unroll
    for (int ni = 0; ni < 4; ++ni) {
      short8v b = *(const short8v*)(Hbuf + swz(fj * 64 + ni * 16 + lr, 32 + lk, 64));
      acc[ni] = __builtin_amdgcn_mfma_f32_16x16x32_bf16(a1, b, acc[ni], 0, 0, 0);
    }
  };

  float4v arE[4], arO[4];   // static reg double-buffer (rule #20)
  const int NT = N / 64;    // 64 (even)

  // prologue: G(0), A(0), G(1), A(1)  -- matches steady-state issue order
  stageH(0, &Hs[0][0]);
  loadA(0, arE);
  stageH(64, &Hs[1][0]);
  loadA(64, arO);

#define K2_BODY(T_, AR_)                                                     \
  {                                                                          \
    const int t_ = (T_);                                                     \
    if (t_ == NT - 1) { asm volatile("s_waitcnt vmcnt(4)" ::: "memory"); }   \
    else              { asm volatile("s_waitcnt vmcnt(12)" ::: "memory"); }  \
    __builtin_amdgcn_s_barrier();                                            \
    if (t_ + 2 < NT) stageH((t_ + 2) * 64, &Hs[(t_ + 2) % 3][0]);            \
    compute(&Hs[t_ % 3][0], AR_);                                            \
    if (t_ + 2 < NT) loadA((t_ + 2) * 64, AR_);                              \
  }

  for (int tt = 0; tt < NT; tt += 2) {
    K2_BODY(tt, arE);
    K2_BODY(tt + 1, arO);
  }
#undef K2_BODY

  // epilogue: bias + relu; D-frag: col(f)=lane&15, row(m)=(lane>>4)*4+r
  float* ob = out + (size_t)batch * N * 128;
#pragma unroll
  for (int ni = 0; ni < 4; ++ni) {
    const int f = fj * 64 + ni * 16 + lr;
    const float bv = bias[f];
    const int mbase = m0 + mi * 16 + (lane >> 4) * 4;
#pragma unroll
    for (int r = 0; r < 4; ++r)
      ob[(size_t)(mbase + r) * 128 + f] = fmaxf(acc[ni][r] + bv, 0.f);
  }
}

extern "C" void kernel_launch(void* const* d_in, const int* in_sizes, int n_in,
                              void* d_out, int out_size, void* d_ws, size_t ws_size,
                              hipStream_t stream) {
  const float* feat = (const float*)d_in[0];  // [B,N,128]
  const float* A    = (const float*)d_in[1];  // [B,N,N]
  const float* W    = (const float*)d_in[2];  // [128,128]
  const float* bias = (const float*)d_in[3];  // [128]
  float* out = (float*)d_out;                 // [B,N,128]

  const int featN = in_sizes[0];      // B*N*128
  const int aN    = in_sizes[1];      // B*N*N
  const int BN    = featN / 128;      // B*N
  const int N     = aN / BN;
  const int Bb    = BN / N;

  short* wt = (short*)d_ws;           // [128][128] bf16 (32 KB)
  short* ht = wt + 128 * 128;         // [B][128][N] bf16

  hipLaunchKernelGGL(k0_wt, dim3(8), dim3(256), 0, stream, W, wt);
  hipLaunchKernelGGL(k1_feat_x_w, dim3(N / 64, Bb), dim3(256), 0, stream, feat, wt, ht, N);
  hipLaunchKernelGGL(k2_a_x_h, dim3(N / 32, Bb), dim3(256), 0, stream, A, ht, bias, out, N);
}

// Round 8
// 100.825 us; speedup vs baseline: 1.1234x; 1.1234x over previous
//
#include <hip/hip_runtime.h>
#include <hip/hip_bf16.h>

typedef __attribute__((ext_vector_type(4))) float  float4v;
typedef __attribute__((ext_vector_type(4))) short  short4v;
typedef __attribute__((ext_vector_type(8))) short  short8v;
typedef __attribute__((ext_vector_type(4))) float  f32x4;

// f32 -> bf16 RTNE via HW cvt (compiler emits v_cvt_pk_bf16_f32)
__device__ __forceinline__ short f2bf(float f) {
  __hip_bfloat16 h = __float2bfloat16(f);
  return *reinterpret_cast<short*>(&h);
}

__device__ __forceinline__ short8v cvt8(float4v v0, float4v v1) {
  short8v s;
  s[0]=f2bf(v0[0]); s[1]=f2bf(v0[1]); s[2]=f2bf(v0[2]); s[3]=f2bf(v0[3]);
  s[4]=f2bf(v1[0]); s[5]=f2bf(v1[1]); s[6]=f2bf(v1[2]); s[7]=f2bf(v1[3]);
  return s;
}

// XOR swizzle for LDS bf16 tiles: short idx k ^= ((row&7)<<3)
__device__ __forceinline__ int swz(int row, int k, int ld) {
  return row * ld + (k ^ ((row & 7) << 3));
}

// async global->LDS, 16B per lane; LDS dest = wave-uniform base + lane*16
__device__ __forceinline__ void gll16(const void* g, void* l) {
  __builtin_amdgcn_global_load_lds(
      (const __attribute__((address_space(1))) unsigned int*)g,
      (__attribute__((address_space(3))) unsigned int*)l, 16, 0, 0);
}

// -------------------------------------------------------------------------
// Kernel 0: wt[f][d] = bf16(W[d][f])  (one-time 128x128 transpose+convert)
// -------------------------------------------------------------------------
__global__ __launch_bounds__(256) void k0_wt(const float* __restrict__ W,
                                             short* __restrict__ wt) {
  const int task = blockIdx.x * 256 + threadIdx.x;   // 2048 tasks
  const int f = task & 127;
  const int dc = (task >> 7) * 8;
  short8v s;
#pragma unroll
  for (int j = 0; j < 8; ++j) s[j] = f2bf(W[(size_t)(dc + j) * 128 + f]);
  *(short8v*)(wt + (size_t)f * 128 + dc) = s;
}

// -------------------------------------------------------------------------
// Kernel 1: ht[b][f][m] = bf16( sum_d feat[b][m][d] * W[d][f] )   (H^T)
// grid (N/64, B), 256 thr. A-frags direct from feat; B-frags direct from
// wt (32 KB, L1-resident). Stores go through an LDS transpose so ht is
// written with fully-coalesced 16B stores.
// -------------------------------------------------------------------------
__global__ __launch_bounds__(256) void k1_feat_x_w(
    const float* __restrict__ feat, const short* __restrict__ wt,
    short* __restrict__ ht, int N) {
  __shared__ short T[128][72];   // [f][m_local], +8 pad (18 KB)
  const int t = threadIdx.x;
  const int batch = blockIdx.y;
  const int m0 = blockIdx.x * 64;
  const int lane = t & 63, wid = t >> 6;
  const int lr = lane & 15, lk = (lane >> 4) * 8;
  const float* pa = feat + (size_t)batch * N * 128
                  + (size_t)(m0 + wid * 16 + lr) * 128 + lk;

  f32x4 acc[8];
#pragma unroll
  for (int j = 0; j < 8; ++j) acc[j] = (f32x4){0.f, 0.f, 0.f, 0.f};

#pragma unroll
  for (int kk = 0; kk < 4; ++kk) {
    float4v v0 = ((const float4v*)(pa + kk * 32))[0];
    float4v v1 = ((const float4v*)(pa + kk * 32))[1];
    short8v a = cvt8(v0, v1);
#pragma unroll
    for (int ni = 0; ni < 8; ++ni) {
      short8v b = *(const short8v*)(wt + (size_t)(ni * 16 + lr) * 128 + kk * 32 + lk);
      acc[ni] = __builtin_amdgcn_mfma_f32_16x16x32_bf16(a, b, acc[ni], 0, 0, 0);
    }
  }

  // deposit: lane holds f=ni*16+lr, m_local = wid*16+(lane>>4)*4+r
  const int mloc = wid * 16 + (lane >> 4) * 4;
#pragma unroll
  for (int ni = 0; ni < 8; ++ni) {
    short4v s;
#pragma unroll
    for (int r = 0; r < 4; ++r) s[r] = f2bf(acc[ni][r]);
    *(short4v*)(&T[ni * 16 + lr][mloc]) = s;
  }
  __syncthreads();

  // coalesced writeout: 1024 (f, m-chunk) slots, 16B each
  short* hb = ht + (size_t)batch * 128 * N;
#pragma unroll
  for (int it = 0; it < 4; ++it) {
    const int idx = it * 256 + t;
    const int f = idx >> 3;
    const int mc = (idx & 7) * 8;
    short8v v = *(const short8v*)(&T[f][mc]);
    *(short8v*)(hb + (size_t)f * N + m0 + mc) = v;
  }
}

// -------------------------------------------------------------------------
// Kernel 2: out[b][m][f] = relu( sum_k A[b][m][k] * H[k][f] + bias[f] )
// grid 512 blocks (2/CU), 256 thr = 4 waves. Tile 64m x 64f; waves
// partition m (16 rows each, NO duplicated A loads). H chunk = 64f x 256k
// bf16 (32 KB) double-buffered via gll16 (pre-swizzled source).
// Barrier period = 4 K-steps (one span): inside a span the code is
// branch-free / barrier-free; A-loads reg-double-buffer 2 steps ahead,
// the next span's first two A-loads issue BEFORE __syncthreads (the
// drain completes them into registers, which legally cross the barrier);
// next H chunk's gll16s get a full span (~12k cy) to land. The per-span
// vmcnt(0) drain is amortized 4x and covered by the other block on the CU.
// -------------------------------------------------------------------------
__global__ __launch_bounds__(256, 2) void k2_a_x_h(
    const float* __restrict__ A, const short* __restrict__ ht,
    const float* __restrict__ bias, float* __restrict__ out, int N) {
  __shared__ __align__(16) short Hs[2][64 * 256];   // 2 x 32 KB
  const int t = threadIdx.x;
  const int lane = t & 63, wid = t >> 6;

  // XCD-chunked swizzle: nwg=512 -> each XCD owns one (batch, f-half) slice
  // of H (512 KB, L2-resident) across all 64 m-tiles.
  const int nwg = gridDim.x;                 // 512
  int wg = blockIdx.x;
  wg = (wg & 7) * (nwg >> 3) + (wg >> 3);
  const int mt = wg & 63;                    // m-tile
  const int ft = (wg >> 6) & 1;              // f-half
  const int batch = wg >> 7;
  const int m0 = mt * 64;
  const int f0 = ft * 64;

  const float* Ab = A + (size_t)batch * N * N;
  const short* hb2 = ht + ((size_t)batch * 128 + f0) * N;

  const int lr = lane & 15, lk = (lane >> 4) * 8;

  const float* pa = Ab + (size_t)(m0 + wid * 16 + lr) * N + lk;

  // stage one 64f x 256k chunk: 8 gll16/wave (wave stages rows wid*16..+15,
  // 2 rows per gll). Source pre-swizzled so linear LDS write lands in swz().
  auto stageH = [&](int k0, int buf) {
    const int hf = lane >> 5;                // row within pair
    const int kk8 = (lane & 31) * 8;         // short offset within row
#pragma unroll
    for (int i = 0; i < 8; ++i) {
      const int r2 = wid * 16 + i * 2;       // wave-uniform row-pair base
      const int frow = r2 + hf;
      const short* g = hb2 + (size_t)frow * N + k0 + (kk8 ^ ((frow & 7) << 3));
      gll16(g, &Hs[buf][r2 * 256]);
    }
  };
  // wave-private A fragments: 16 rows x 64 k -> 4 dwordx4 per lane
  auto loadA = [&](int k0, float4v (&ar)[4]) {
    const float* p = pa + k0;
    ar[0] = ((const float4v*)p)[0];
    ar[1] = ((const float4v*)p)[1];
    ar[2] = ((const float4v*)(p + 32))[0];
    ar[3] = ((const float4v*)(p + 32))[1];
  };

  f32x4 acc[4];
#pragma unroll
  for (int j = 0; j < 4; ++j) acc[j] = (f32x4){0.f, 0.f, 0.f, 0.f};

  // one K-step (64 k) from LDS chunk at local step s (0..3)
  auto compute = [&](int buf, int s, float4v (&ar)[4]) {
    short8v a0 = cvt8(ar[0], ar[1]);
    short8v a1 = cvt8(ar[2], ar[3]);
    const short* Hb = &Hs[buf][0];
#pragma unroll
    for (int ni = 0; ni < 4; ++ni) {
      short8v b = *(const short8v*)(Hb + swz(ni * 16 + lr, s * 64 + lk, 256));
      acc[ni] = __builtin_amdgcn_mfma_f32_16x16x32_bf16(a0, b, acc[ni], 0, 0, 0);
    }
#pragma unroll
    for (int ni = 0; ni < 4; ++ni) {
      short8v b = *(const short8v*)(Hb + swz(ni * 16 + lr, s * 64 + 32 + lk, 256));
      acc[ni] = __builtin_amdgcn_mfma_f32_16x16x32_bf16(a1, b, acc[ni], 0, 0, 0);
    }
  };

  float4v arA[4], arB[4];       // static reg double-buffer (rule #20)
  const int NSPAN = N / 256;    // 16

  // prologue: chunk 0 staged; A(step0), A(step1) loaded (drained by barrier
  // into registers -- that's fine, they cross the barrier as data).
  stageH(0, 0);
  loadA(0, arA);
  loadA(64, arB);
  __syncthreads();

  for (int c = 0; c < NSPAN - 1; ++c) {
    const int buf = c & 1;
    const int kc = c * 256;
    stageH(kc + 256, buf ^ 1);          // next chunk: lands over this span
    compute(buf, 0, arA);  loadA(kc + 128, arA);
    compute(buf, 1, arB);  loadA(kc + 192, arB);
    compute(buf, 2, arA);  loadA(kc + 256, arA);        // next span s0
    compute(buf, 3, arB);  loadA(kc + 320, arB);        // next span s1
    __syncthreads();                    // drains gll(next) + A prefetches
  }
  {  // peeled last span (no further prefetch)
    const int buf = (NSPAN - 1) & 1;
    const int kc = (NSPAN - 1) * 256;
    compute(buf, 0, arA);  loadA(kc + 128, arA);
    compute(buf, 1, arB);  loadA(kc + 192, arB);
    compute(buf, 2, arA);
    compute(buf, 3, arB);
  }

  // epilogue: bias + relu; D-frag: col(f)=lane&15, row(m)=(lane>>4)*4+r
  float* ob = out + (size_t)batch * N * 128;
#pragma unroll
  for (int ni = 0; ni < 4; ++ni) {
    const int f = f0 + ni * 16 + lr;
    const float bv = bias[f];
    const int mbase = m0 + wid * 16 + (lane >> 4) * 4;
#pragma unroll
    for (int r = 0; r < 4; ++r)
      ob[(size_t)(mbase + r) * 128 + f] = fmaxf(acc[ni][r] + bv, 0.f);
  }
}

extern "C" void kernel_launch(void* const* d_in, const int* in_sizes, int n_in,
                              void* d_out, int out_size, void* d_ws, size_t ws_size,
                              hipStream_t stream) {
  const float* feat = (const float*)d_in[0];  // [B,N,128]
  const float* A    = (const float*)d_in[1];  // [B,N,N]
  const float* W    = (const float*)d_in[2];  // [128,128]
  const float* bias = (const float*)d_in[3];  // [128]
  float* out = (float*)d_out;                 // [B,N,128]

  const int featN = in_sizes[0];      // B*N*128
  const int aN    = in_sizes[1];      // B*N*N
  const int BN    = featN / 128;      // B*N
  const int N     = aN / BN;
  const int Bb    = BN / N;

  short* wt = (short*)d_ws;           // [128][128] bf16 (32 KB)
  short* ht = wt + 128 * 128;         // [B][128][N] bf16

  hipLaunchKernelGGL(k0_wt, dim3(8), dim3(256), 0, stream, W, wt);
  hipLaunchKernelGGL(k1_feat_x_w, dim3(N / 64, Bb), dim3(256), 0, stream, feat, wt, ht, N);
  hipLaunchKernelGGL(k2_a_x_h, dim3((N / 64) * 2 * Bb), dim3(256), 0, stream, A, ht, bias, out, N);
}

// Round 9
// 95.628 us; speedup vs baseline: 1.1845x; 1.0543x over previous
//
#include <hip/hip_runtime.h>
#include <hip/hip_bf16.h>

typedef __attribute__((ext_vector_type(4))) float  float4v;
typedef __attribute__((ext_vector_type(4))) short  short4v;
typedef __attribute__((ext_vector_type(8))) short  short8v;
typedef __attribute__((ext_vector_type(4))) float  f32x4;

// f32 -> bf16 RTNE via HW cvt (compiler emits v_cvt_pk_bf16_f32)
__device__ __forceinline__ short f2bf(float f) {
  __hip_bfloat16 h = __float2bfloat16(f);
  return *reinterpret_cast<short*>(&h);
}

__device__ __forceinline__ short8v cvt8(float4v v0, float4v v1) {
  short8v s;
  s[0]=f2bf(v0[0]); s[1]=f2bf(v0[1]); s[2]=f2bf(v0[2]); s[3]=f2bf(v0[3]);
  s[4]=f2bf(v1[0]); s[5]=f2bf(v1[1]); s[6]=f2bf(v1[2]); s[7]=f2bf(v1[3]);
  return s;
}

// XOR swizzle for LDS bf16 tiles: short idx k ^= ((row&7)<<3)
__device__ __forceinline__ int swz(int row, int k, int ld) {
  return row * ld + (k ^ ((row & 7) << 3));
}

// async global->LDS, 16B per lane; LDS dest = wave-uniform base + lane*16
__device__ __forceinline__ void gll16(const void* g, void* l) {
  __builtin_amdgcn_global_load_lds(
      (const __attribute__((address_space(1))) unsigned int*)g,
      (__attribute__((address_space(3))) unsigned int*)l, 16, 0, 0);
}

// -------------------------------------------------------------------------
// Kernel 0: wt[f][d] = bf16(W[d][f])  (one-time 128x128 transpose+convert)
// -------------------------------------------------------------------------
__global__ __launch_bounds__(256) void k0_wt(const float* __restrict__ W,
                                             short* __restrict__ wt) {
  const int task = blockIdx.x * 256 + threadIdx.x;   // 2048 tasks
  const int f = task & 127;
  const int dc = (task >> 7) * 8;
  short8v s;
#pragma unroll
  for (int j = 0; j < 8; ++j) s[j] = f2bf(W[(size_t)(dc + j) * 128 + f]);
  *(short8v*)(wt + (size_t)f * 128 + dc) = s;
}

// -------------------------------------------------------------------------
// Kernel 1: ht[b][f][m] = bf16( sum_d feat[b][m][d] * W[d][f] )   (H^T)
// grid (N/64, B), 256 thr. A-frags direct from feat; B-frags direct from
// wt (32 KB, L1-resident). Stores through an LDS transpose -> coalesced.
// -------------------------------------------------------------------------
__global__ __launch_bounds__(256) void k1_feat_x_w(
    const float* __restrict__ feat, const short* __restrict__ wt,
    short* __restrict__ ht, int N) {
  __shared__ short T[128][72];   // [f][m_local], +8 pad (18 KB)
  const int t = threadIdx.x;
  const int batch = blockIdx.y;
  const int m0 = blockIdx.x * 64;
  const int lane = t & 63, wid = t >> 6;
  const int lr = lane & 15, lk = (lane >> 4) * 8;
  const float* pa = feat + (size_t)batch * N * 128
                  + (size_t)(m0 + wid * 16 + lr) * 128 + lk;

  f32x4 acc[8];
#pragma unroll
  for (int j = 0; j < 8; ++j) acc[j] = (f32x4){0.f, 0.f, 0.f, 0.f};

#pragma unroll
  for (int kk = 0; kk < 4; ++kk) {
    float4v v0 = ((const float4v*)(pa + kk * 32))[0];
    float4v v1 = ((const float4v*)(pa + kk * 32))[1];
    short8v a = cvt8(v0, v1);
#pragma unroll
    for (int ni = 0; ni < 8; ++ni) {
      short8v b = *(const short8v*)(wt + (size_t)(ni * 16 + lr) * 128 + kk * 32 + lk);
      acc[ni] = __builtin_amdgcn_mfma_f32_16x16x32_bf16(a, b, acc[ni], 0, 0, 0);
    }
  }

  const int mloc = wid * 16 + (lane >> 4) * 4;
#pragma unroll
  for (int ni = 0; ni < 8; ++ni) {
    short4v s;
#pragma unroll
    for (int r = 0; r < 4; ++r) s[r] = f2bf(acc[ni][r]);
    *(short4v*)(&T[ni * 16 + lr][mloc]) = s;
  }
  __syncthreads();

  short* hb = ht + (size_t)batch * 128 * N;
#pragma unroll
  for (int it = 0; it < 4; ++it) {
    const int idx = it * 256 + t;
    const int f = idx >> 3;
    const int mc = (idx & 7) * 8;
    short8v v = *(const short8v*)(&T[f][mc]);
    *(short8v*)(hb + (size_t)f * N + m0 + mc) = v;
  }
}

// -------------------------------------------------------------------------
// Kernel 2: partial[kh][b][m][f] (NSPLIT=2) or fused out (NSPLIT=1).
// R2-proven structure: tile 32m x 128f, BK=64, double-buffered LDS,
// A reg-staged, H via gll16 (pre-swizzled source), ALL prefetch issued at
// step START (so the barrier's vmcnt(0) drain is nearly free), one
// __syncthreads per step. NSPLIT=2 halves each block's K-range ->
// grid 1024 = 4 blocks/CU (LDS 40KB x 4 = 160KB exact), doubling
// independent barrier domains and in-flight HBM requests with ZERO
// change in total A/H bytes.
// -------------------------------------------------------------------------
template<int NSPLIT>
__global__ __launch_bounds__(256, 4) void k2_a_x_h(
    const float* __restrict__ A, const short* __restrict__ ht,
    const float* __restrict__ bias, float* __restrict__ dst, int N) {
  __shared__ __align__(16) short As[2][32 * 64];    // 2 x 4 KB
  __shared__ __align__(16) short Hs[2][128 * 64];   // 2 x 16 KB
  const int t = threadIdx.x;

  // XCD-chunked swizzle (nwg multiple of 8 -> bijective). Consecutive
  // swizzled wg share (batch, kh) -> one 512KB H-slice per XCD chunk.
  const int nwg = gridDim.x * gridDim.y;
  int wg = blockIdx.x + gridDim.x * blockIdx.y;
  wg = (wg & 7) * (nwg >> 3) + (wg >> 3);
  const int mtiles = gridDim.x;
  const int combo = wg / mtiles;
  const int kh = (NSPLIT == 2) ? (combo & 1) : 0;
  const int batch = (NSPLIT == 2) ? (combo >> 1) : combo;
  const int m0 = (wg - combo * mtiles) * 32;
  const int kbase = kh * (N / NSPLIT);

  const float* Ab = A + (size_t)batch * N * N;
  const short* hb = ht + (size_t)batch * 128 * N;

  const int lane = t & 63, wid = t >> 6;
  const int mi = wid >> 1, fj = wid & 1;
  const int lr = lane & 15, lk = (lane >> 4) * 8;

  // A staging map: thread covers 8 consecutive f32 (2x dwordx4)
  const int arow = t >> 3;        // 0..31
  const int akc = (t & 7) * 8;

  // H staging map (per wave, 4 gll16 calls of 16B/lane):
  const int hf = lane >> 3;          // 0..7
  const int hks = (lane & 7) * 8;    // k slot (shorts)

  float4v va0, va1;
  auto loadA = [&](int k0) {
    const float* p = Ab + (size_t)(m0 + arow) * N + k0 + akc;
    va0 = ((const float4v*)p)[0];
    va1 = ((const float4v*)p)[1];
  };
  auto writeA = [&](int buf) {
    *(short8v*)(&As[buf][swz(arow, akc, 64)]) = cvt8(va0, va1);
  };
  auto stageH = [&](int k0, int buf) {
#pragma unroll
    for (int i = 0; i < 4; ++i) {
      const int fb8 = (wid * 4 + i) * 8;         // wave-uniform f base
      const int f = fb8 + hf;
      const short* g = hb + (size_t)f * N + k0 + (hks ^ (hf << 3));
      gll16(g, &Hs[buf][fb8 * 64]);
    }
  };

  f32x4 acc[4];
#pragma unroll
  for (int j = 0; j < 4; ++j) acc[j] = (f32x4){0.f, 0.f, 0.f, 0.f};

  // prologue: tile 0 into buf 0 (all prefetch at start)
  loadA(kbase);
  stageH(kbase, 0);
  writeA(0);
  __syncthreads();

  const int NT = (N / NSPLIT) / 64;
  for (int tt = 0; tt < NT; ++tt) {
    const int cur = tt & 1;
    const bool pf = (tt + 1 < NT);
    if (pf) {
      loadA(kbase + (tt + 1) * 64);   // issued at step start
      stageH(kbase + (tt + 1) * 64, cur ^ 1);
    }
#pragma unroll
    for (int kk = 0; kk < 2; ++kk) {
      const int k = kk * 32 + lk;
      short8v a = *(const short8v*)(&As[cur][swz(mi * 16 + lr, k, 64)]);
#pragma unroll
      for (int ni = 0; ni < 4; ++ni) {
        short8v b = *(const short8v*)(&Hs[cur][swz(fj * 64 + ni * 16 + lr, k, 64)]);
        acc[ni] = __builtin_amdgcn_mfma_f32_16x16x32_bf16(a, b, acc[ni], 0, 0, 0);
      }
    }
    if (pf) writeA(cur ^ 1);
    __syncthreads();
  }

  // epilogue; D-frag: col(f)=lane&15, row(m)=(lane>>4)*4+r
  if (NSPLIT == 2) {
    float* pb = dst + ((size_t)kh * gridDim.y / 2 * mtiles * 32 + (size_t)batch * N) * 128;
#pragma unroll
    for (int ni = 0; ni < 4; ++ni) {
      const int f = fj * 64 + ni * 16 + lr;
      const int mbase = m0 + mi * 16 + (lane >> 4) * 4;
#pragma unroll
      for (int r = 0; r < 4; ++r)
        pb[(size_t)(mbase + r) * 128 + f] = acc[ni][r];
    }
  } else {
    float* ob = dst + (size_t)batch * N * 128;
#pragma unroll
    for (int ni = 0; ni < 4; ++ni) {
      const int f = fj * 64 + ni * 16 + lr;
      const float bv = bias[f];
      const int mbase = m0 + mi * 16 + (lane >> 4) * 4;
#pragma unroll
      for (int r = 0; r < 4; ++r)
        ob[(size_t)(mbase + r) * 128 + f] = fmaxf(acc[ni][r] + bv, 0.f);
    }
  }
}

// -------------------------------------------------------------------------
// Kernel 3: out = relu(p0 + p1 + bias)  (float4 grid-stride; partials L2/L3)
// -------------------------------------------------------------------------
__global__ __launch_bounds__(256) void k3_combine(
    const float* __restrict__ p0, const float* __restrict__ p1,
    const float* __restrict__ bias, float* __restrict__ out, long total4) {
  const long stride = (long)gridDim.x * 256;
  for (long i = blockIdx.x * 256L + threadIdx.x; i < total4; i += stride) {
    float4v a = ((const float4v*)p0)[i];
    float4v b = ((const float4v*)p1)[i];
    float4v bv = ((const float4v*)bias)[i & 31];
    float4v o;
#pragma unroll
    for (int j = 0; j < 4; ++j) o[j] = fmaxf(a[j] + b[j] + bv[j], 0.f);
    ((float4v*)out)[i] = o;
  }
}

extern "C" void kernel_launch(void* const* d_in, const int* in_sizes, int n_in,
                              void* d_out, int out_size, void* d_ws, size_t ws_size,
                              hipStream_t stream) {
  const float* feat = (const float*)d_in[0];  // [B,N,128]
  const float* A    = (const float*)d_in[1];  // [B,N,N]
  const float* W    = (const float*)d_in[2];  // [128,128]
  const float* bias = (const float*)d_in[3];  // [128]
  float* out = (float*)d_out;                 // [B,N,128]

  const int featN = in_sizes[0];      // B*N*128
  const int aN    = in_sizes[1];      // B*N*N
  const int BN    = featN / 128;      // B*N
  const int N     = aN / BN;
  const int Bb    = BN / N;

  short* wt = (short*)d_ws;           // [128][128] bf16 (32 KB)
  short* ht = wt + 128 * 128;         // [B][128][N] bf16
  float* part = (float*)(ht + (size_t)Bb * 128 * N);  // [2][B][N][128] f32

  const size_t need = 128 * 128 * 2 + (size_t)Bb * 128 * N * 2
                    + (size_t)2 * Bb * N * 128 * 4;

  hipLaunchKernelGGL(k0_wt, dim3(8), dim3(256), 0, stream, W, wt);
  hipLaunchKernelGGL(k1_feat_x_w, dim3(N / 64, Bb), dim3(256), 0, stream, feat, wt, ht, N);

  if (ws_size >= need && (N / 32) % 1 == 0) {
    // split-K x2: 4 blocks/CU, zero traffic inflation
    hipLaunchKernelGGL((k2_a_x_h<2>), dim3(N / 32, 2 * Bb), dim3(256), 0, stream,
                       A, ht, bias, part, N);
    const long total4 = (long)Bb * N * 32;   // float4 count
    hipLaunchKernelGGL(k3_combine, dim3(2048), dim3(256), 0, stream,
                       part, part + (size_t)Bb * N * 128, bias, out, total4);
  } else {
    // fallback: proven R2 path
    hipLaunchKernelGGL((k2_a_x_h<1>), dim3(N / 32, Bb), dim3(256), 0, stream,
                       A, ht, bias, out, N);
  }
}

// Round 10
// 89.739 us; speedup vs baseline: 1.2622x; 1.0656x over previous
//
#include <hip/hip_runtime.h>
#include <hip/hip_bf16.h>

typedef __attribute__((ext_vector_type(4))) float  float4v;
typedef __attribute__((ext_vector_type(4))) short  short4v;
typedef __attribute__((ext_vector_type(8))) short  short8v;
typedef __attribute__((ext_vector_type(4))) float  f32x4;

// f32 -> bf16 RTNE via HW cvt (compiler emits v_cvt_pk_bf16_f32)
__device__ __forceinline__ short f2bf(float f) {
  __hip_bfloat16 h = __float2bfloat16(f);
  return *reinterpret_cast<short*>(&h);
}

__device__ __forceinline__ short8v cvt8(float4v v0, float4v v1) {
  short8v s;
  s[0]=f2bf(v0[0]); s[1]=f2bf(v0[1]); s[2]=f2bf(v0[2]); s[3]=f2bf(v0[3]);
  s[4]=f2bf(v1[0]); s[5]=f2bf(v1[1]); s[6]=f2bf(v1[2]); s[7]=f2bf(v1[3]);
  return s;
}

// XOR swizzle for bf16 LDS tiles: short idx k ^= ((row&7)<<3)
__device__ __forceinline__ int swz(int row, int k, int ld) {
  return row * ld + (k ^ ((row & 7) << 3));
}

// async global->LDS, 16B per lane; LDS dest = wave-uniform base + lane*16
__device__ __forceinline__ void gll16(const void* g, void* l) {
  __builtin_amdgcn_global_load_lds(
      (const __attribute__((address_space(1))) unsigned int*)g,
      (__attribute__((address_space(3))) unsigned int*)l, 16, 0, 0);
}

// -------------------------------------------------------------------------
// Kernel 0: wt[f][d] = bf16(W[d][f])  (one-time 128x128 transpose+convert)
// -------------------------------------------------------------------------
__global__ __launch_bounds__(256) void k0_wt(const float* __restrict__ W,
                                             short* __restrict__ wt) {
  const int task = blockIdx.x * 256 + threadIdx.x;   // 2048 tasks
  const int f = task & 127;
  const int dc = (task >> 7) * 8;
  short8v s;
#pragma unroll
  for (int j = 0; j < 8; ++j) s[j] = f2bf(W[(size_t)(dc + j) * 128 + f]);
  *(short8v*)(wt + (size_t)f * 128 + dc) = s;
}

// -------------------------------------------------------------------------
// Kernel 1: ht[b][f][m] = bf16( sum_d feat[b][m][d] * W[d][f] )   (H^T)
// grid (N/64, B), 256 thr. A-frags direct from feat; B-frags direct from
// wt (32 KB, L1-resident). Stores through an LDS transpose -> coalesced.
// -------------------------------------------------------------------------
__global__ __launch_bounds__(256) void k1_feat_x_w(
    const float* __restrict__ feat, const short* __restrict__ wt,
    short* __restrict__ ht, int N) {
  __shared__ short T[128][72];   // [f][m_local], +8 pad (18 KB)
  const int t = threadIdx.x;
  const int batch = blockIdx.y;
  const int m0 = blockIdx.x * 64;
  const int lane = t & 63, wid = t >> 6;
  const int lr = lane & 15, lk = (lane >> 4) * 8;
  const float* pa = feat + (size_t)batch * N * 128
                  + (size_t)(m0 + wid * 16 + lr) * 128 + lk;

  f32x4 acc[8];
#pragma unroll
  for (int j = 0; j < 8; ++j) acc[j] = (f32x4){0.f, 0.f, 0.f, 0.f};

#pragma unroll
  for (int kk = 0; kk < 4; ++kk) {
    float4v v0 = ((const float4v*)(pa + kk * 32))[0];
    float4v v1 = ((const float4v*)(pa + kk * 32))[1];
    short8v a = cvt8(v0, v1);
#pragma unroll
    for (int ni = 0; ni < 8; ++ni) {
      short8v b = *(const short8v*)(wt + (size_t)(ni * 16 + lr) * 128 + kk * 32 + lk);
      acc[ni] = __builtin_amdgcn_mfma_f32_16x16x32_bf16(a, b, acc[ni], 0, 0, 0);
    }
  }

  const int mloc = wid * 16 + (lane >> 4) * 4;
#pragma unroll
  for (int ni = 0; ni < 8; ++ni) {
    short4v s;
#pragma unroll
    for (int r = 0; r < 4; ++r) s[r] = f2bf(acc[ni][r]);
    *(short4v*)(&T[ni * 16 + lr][mloc]) = s;
  }
  __syncthreads();

  short* hb = ht + (size_t)batch * 128 * N;
#pragma unroll
  for (int it = 0; it < 4; ++it) {
    const int idx = it * 256 + t;
    const int f = idx >> 3;
    const int mc = (idx & 7) * 8;
    short8v v = *(const short8v*)(&T[f][mc]);
    *(short8v*)(hb + (size_t)f * N + m0 + mc) = v;
  }
}

// -------------------------------------------------------------------------
// Kernel 2: out[b][m][f] = relu( sum_k A[b][m][k] * H[k][f] + bias[f] )
// grid (N/32, B) = 512 blocks (2/CU), 256 thr = 4 waves. Tile 32m x 128f,
// BK=64, double-buffered LDS, one __syncthreads per K-step (champion R2
// topology). DELTA vs R2: A is staged via global_load_lds as RAW F32
// (16B-swizzled dest via pre-swizzled source) and converted f32->bf16
// AFTER the LDS read. The step body now has ZERO vmem->register
// dependencies, so the only wait is the barrier's own vmcnt(0) drain,
// whose latency is covered by the compute phase + the co-resident block.
// -------------------------------------------------------------------------
__global__ __launch_bounds__(256, 4) void k2_a_x_h(
    const float* __restrict__ A, const short* __restrict__ ht,
    const float* __restrict__ bias, float* __restrict__ out, int N) {
  __shared__ __align__(16) float Asf[2][32 * 64];   // f32 A tile, 2 x 8 KB
  __shared__ __align__(16) short Hs[2][128 * 64];   // bf16 H^T tile, 2 x 16 KB
  const int t = threadIdx.x;
  const int lane = t & 63, wid = t >> 6;
  const int mi = wid >> 1, fj = wid & 1;

  // XCD-chunked swizzle (nwg = 512, multiple of 8 -> bijective); each XCD
  // gets 64 consecutive m-tiles of one batch -> 1 MB H slice L2-resident.
  const int nwg = gridDim.x * gridDim.y;
  int wg = blockIdx.x + gridDim.x * blockIdx.y;
  wg = (wg & 7) * (nwg >> 3) + (wg >> 3);
  const int mtiles = gridDim.x;
  const int batch = wg / mtiles;
  const int m0 = (wg - batch * mtiles) * 32;

  const float* Ab = A + (size_t)batch * N * N;
  const short* hb = ht + (size_t)batch * 128 * N;

  const int lr = lane & 15, lk = (lane >> 4) * 8;

  // ---- A staging: 2 gll16/wave, 4 rows each; dest linear, source carries
  // the inverse of the 16B-granular XOR swizzle (byte ^= (row&7)<<4).
  const int ar = lane >> 4;            // row within 4-row group (0..3)
  const int ac = (lane & 15) * 4;      // f32 col of this lane's 16B chunk
  auto stageA = [&](int k0, int buf) {
#pragma unroll
    for (int i = 0; i < 2; ++i) {
      const int r4 = wid * 8 + i * 4;  // wave-uniform row base
      const int row = r4 + ar;
      const float* g = Ab + (size_t)(m0 + row) * N + k0
                     + (ac ^ ((row & 7) << 2));
      gll16(g, &Asf[buf][r4 * 64]);
    }
  };
  // ---- H staging: 4 gll16/wave, 8 f-rows each (champion-proven map).
  const int hf = lane >> 3;            // 0..7
  const int hks = (lane & 7) * 8;      // short col of this lane's 16B chunk
  auto stageH = [&](int k0, int buf) {
#pragma unroll
    for (int i = 0; i < 4; ++i) {
      const int fb8 = (wid * 4 + i) * 8;
      const int f = fb8 + hf;
      const short* g = hb + (size_t)f * N + k0 + (hks ^ (hf << 3));
      gll16(g, &Hs[buf][fb8 * 64]);
    }
  };

  // swizzled 16B read of A tile: row r, f32 col c0 (4-aligned)
  auto rdA = [&](int buf, int r, int c0) -> float4v {
    const char* base = (const char*)&Asf[buf][0];
    return *(const float4v*)(base + r * 256 + ((c0 * 4) ^ ((r & 7) << 4)));
  };

  f32x4 acc[4];
#pragma unroll
  for (int j = 0; j < 4; ++j) acc[j] = (f32x4){0.f, 0.f, 0.f, 0.f};

  // prologue: tile 0 into buf 0 (all gll; drained by the first barrier)
  stageA(0, 0);
  stageH(0, 0);
  __syncthreads();

  const int NT = N / 64;
  const int arow = mi * 16 + lr;
  for (int tt = 0; tt < NT; ++tt) {
    const int cur = tt & 1;
    if (tt + 1 < NT) {                 // issue next tile at step START
      stageA((tt + 1) * 64, cur ^ 1);
      stageH((tt + 1) * 64, cur ^ 1);
    }
#pragma unroll
    for (int kk = 0; kk < 2; ++kk) {
      const int k = kk * 32 + lk;
      float4v a0 = rdA(cur, arow, k);
      float4v a1 = rdA(cur, arow, k + 4);
      short8v a = cvt8(a0, a1);
#pragma unroll
      for (int ni = 0; ni < 4; ++ni) {
        short8v b = *(const short8v*)(&Hs[cur][swz(fj * 64 + ni * 16 + lr, k, 64)]);
        acc[ni] = __builtin_amdgcn_mfma_f32_16x16x32_bf16(a, b, acc[ni], 0, 0, 0);
      }
    }
    __syncthreads();                   // drains next tile's gll writes
  }

  // epilogue: bias + relu; D-frag: col(f)=lane&15, row(m)=(lane>>4)*4+r
  float* ob = out + (size_t)batch * N * 128;
#pragma unroll
  for (int ni = 0; ni < 4; ++ni) {
    const int f = fj * 64 + ni * 16 + lr;
    const float bv = bias[f];
    const int mbase = m0 + mi * 16 + (lane >> 4) * 4;
#pragma unroll
    for (int r = 0; r < 4; ++r)
      ob[(size_t)(mbase + r) * 128 + f] = fmaxf(acc[ni][r] + bv, 0.f);
  }
}

extern "C" void kernel_launch(void* const* d_in, const int* in_sizes, int n_in,
                              void* d_out, int out_size, void* d_ws, size_t ws_size,
                              hipStream_t stream) {
  const float* feat = (const float*)d_in[0];  // [B,N,128]
  const float* A    = (const float*)d_in[1];  // [B,N,N]
  const float* W    = (const float*)d_in[2];  // [128,128]
  const float* bias = (const float*)d_in[3];  // [128]
  float* out = (float*)d_out;                 // [B,N,128]

  const int featN = in_sizes[0];      // B*N*128
  const int aN    = in_sizes[1];      // B*N*N
  const int BN    = featN / 128;      // B*N
  const int N     = aN / BN;
  const int Bb    = BN / N;

  short* wt = (short*)d_ws;           // [128][128] bf16 (32 KB)
  short* ht = wt + 128 * 128;         // [B][128][N] bf16

  hipLaunchKernelGGL(k0_wt, dim3(8), dim3(256), 0, stream, W, wt);
  hipLaunchKernelGGL(k1_feat_x_w, dim3(N / 64, Bb), dim3(256), 0, stream, feat, wt, ht, N);
  hipLaunchKernelGGL(k2_a_x_h, dim3(N / 32, Bb), dim3(256), 0, stream, A, ht, bias, out, N);
}